// Round 1
// baseline (163.281 us; speedup 1.0000x reference)
//
#include <hip/hip_runtime.h>

typedef unsigned short u16;
typedef unsigned int   u32;
typedef __attribute__((ext_vector_type(8))) short short8;   // 8 bf16 = 4 VGPRs
typedef __attribute__((ext_vector_type(4))) float f32x4;

#define NB    4      // batch
#define NCH   256    // channels
#define NHD   8      // heads
#define HD    32     // head dim
#define NSP   2304   // H*W
#define NBH   32     // NB*NHD
#define NKT   36     // total 64-wide K tiles
#define KPW   9      // K tiles per wave (4-wave in-block k-split)

// round-to-nearest-even fp32 -> bf16 bits
__device__ __forceinline__ u16 f2bf(float f) {
    u32 u = __float_as_uint(f);
    u += 0x7FFFu + ((u >> 16) & 1u);
    return (u16)(u >> 16);
}
__device__ __forceinline__ u32 pack2(float a, float b) {
    return (u32)f2bf(a) | ((u32)f2bf(b) << 16);
}
// fast pack two fp32 -> bf16x2: hw cvt (RNE) if present, else 1-instr v_perm truncate.
__device__ __forceinline__ u32 pkfast(float a, float b) {
#if __has_builtin(__builtin_amdgcn_cvt_pk_bf16_f32)
    typedef __attribute__((ext_vector_type(2))) __bf16 bf2;
    union { bf2 v; u32 u; } cv;
    cv.v = __builtin_amdgcn_cvt_pk_bf16_f32(a, b);
    return cv.u;
#else
    return __builtin_amdgcn_perm(__float_as_uint(b), __float_as_uint(a), 0x07060302u);
#endif
}
__device__ __forceinline__ float fexp2(float x) {
#if __has_builtin(__builtin_amdgcn_exp2f)
    return __builtin_amdgcn_exp2f(x);
#else
    return exp2f(x);
#endif
}

// ---------------- prep: normalize q,k (temp*log2e folded into q); v -> sigma-permuted
// tiles; p==3 slice casts proj_w -> bf16.
// Two spatial columns per thread (float2 loads halve VMEM instr count vs scalar).
// grid (6, 4, NBH), block 192: 6*192*2 = 2304 = NSP.
__global__ __launch_bounds__(192) void prep_kernel(
    const float* __restrict__ qkv, const float* __restrict__ temp,
    const float* __restrict__ projw,
    u16* __restrict__ Qn, u16* __restrict__ Kn, u16* __restrict__ Vp,
    u16* __restrict__ Wb)
{
    const int p  = blockIdx.y;
    const int bh = blockIdx.z, b = bh >> 3, head = bh & 7;

    if (p == 3) {   // proj_w cast: 16384 float4 chunks spread over 6*32 blocks
        const int idx = (bh * 6 + blockIdx.x) * 192 + threadIdx.x;
        if (idx < NCH * NCH / 4) {
            float4 v = ((const float4*)projw)[idx];
            ((uint2*)Wb)[idx] = make_uint2(pack2(v.x, v.y), pack2(v.z, v.w));
        }
        return;
    }

    const int i  = blockIdx.x * 192 + threadIdx.x;   // [0, 1152)
    const int n0 = i * 2;                            // even spatial index; pair (n0, n0+1)
    const float* src = qkv + ((size_t)(b * 3 * NCH + p * NCH + head * HD)) * NSP + n0;

    float2 v[HD];
#pragma unroll
    for (int d = 0; d < HD; ++d) v[d] = *(const float2*)(src + (size_t)d * NSP);

    if (p == 2) {
        // V tile layout: Vp[bh][kt][d*64 + c*32 + quad*8 + jj]; for even n0 the pair
        // (n0, n0+1) maps to adjacent u16 slots (jj even -> jj, jj+1 in the same
        // c/quad; proven over all even loc in [0,62]) -> one aligned u32 store.
        const int tile = n0 >> 6, loc = n0 & 63;
        const int c = loc >> 5, r5 = loc & 31;
        const int qd  = (r5 < 16) ? (r5 >> 2) : ((r5 - 16) >> 2);
        const int jj  = (r5 < 16) ? (r5 & 3) : (4 + (r5 & 3));
        u16* dst = Vp + (size_t)bh * NSP * HD + (size_t)tile * 2048 + c * 32 + qd * 8 + jj;
#pragma unroll
        for (int d = 0; d < HD; ++d) *(u32*)(dst + d * 64) = pack2(v[d].x, v[d].y);
    } else {
        float s0 = 0.f, s1 = 0.f;
#pragma unroll
        for (int d = 0; d < HD; ++d) { s0 += v[d].x * v[d].x; s1 += v[d].y * v[d].y; }
        float sc0 = 1.f / fmaxf(sqrtf(s0), 1e-12f);
        float sc1 = 1.f / fmaxf(sqrtf(s1), 1e-12f);
        if (p == 0) {   // fold temp*log2e into q
            const float t = temp[head] * 1.44269504088896f;
            sc0 *= t; sc1 *= t;
        }
        u32 pk[HD];   // [0..15] row n0, [16..31] row n0+1
#pragma unroll
        for (int j = 0; j < HD / 2; ++j) pk[j]          = pack2(v[2 * j].x * sc0, v[2 * j + 1].x * sc0);
#pragma unroll
        for (int j = 0; j < HD / 2; ++j) pk[HD / 2 + j] = pack2(v[2 * j].y * sc1, v[2 * j + 1].y * sc1);
        u16* dst = (p == 0 ? Qn : Kn) + ((size_t)bh * NSP + n0) * HD;   // 2 rows = 128 B contiguous
#pragma unroll
        for (int j = 0; j < 8; ++j) ((uint4*)dst)[j] = ((const uint4*)pk)[j];
    }
}

// ---------------- flash attention: 64 q-rows/wave, 4-way k-split, barrier-free K-loop ----
// block = 256 thr (4 waves), grid (NBH, NSP/64). blockIdx.x = bh so all q-blocks of a bh
// share one XCD -> K/V L2-resident.
// All 4 waves own the SAME 64 q-rows; wave w covers k-tiles [w*9,w*9+9).
// Partials combine linearly (exp(relu)/sum: no running max).
// Epilogue is TWO-PHASE to halve LDS (50176 -> 25600 B): publish+reduce t2={0,1}, barrier,
// publish+reduce t2={2,3}. LDS cap was 3 blocks/CU (two-round schedule, Occupancy 16%,
// VALUBusy 61%); 25.6 KB + launch_bounds(256,4) gives 4 blocks/CU (1152/1024 = 1.125
// rounds). K-loop itself stays barrier-free.
__global__ __launch_bounds__(256, 4) void attn_kernel(
    const u16* __restrict__ Qn, const u16* __restrict__ Kn,
    const u16* __restrict__ Vp, u16* __restrict__ X)
{
    __shared__ float cmb[4][64][25];   // [wave][lane][tt*12 + {8 O0,O1 | 4 rs}] pad 25
    const int bh = blockIdx.x, b = bh >> 3, head = bh & 7;
    const int w = threadIdx.x >> 6, lane = threadIdx.x & 63;
    const int l15 = lane & 15, quad = lane >> 4;
    const int qbase = blockIdx.y * 64;

    const u16* Kg = Kn + (size_t)bh * NSP * HD + (size_t)w * KPW * 2048 + l15 * HD + quad * 8;
    const u16* Vg = Vp + (size_t)bh * NSP * HD + (size_t)w * KPW * 2048 + l15 * 64 + quad * 8;

    short8 qf[4];
#pragma unroll
    for (int t2 = 0; t2 < 4; ++t2)
        qf[t2] = *(const short8*)(Qn + ((size_t)bh * NSP + qbase + t2 * 16 + l15) * HD + quad * 8);

    const short one = (short)0x3F80;   // bf16 1.0
    const short8 vones = {one, one, one, one, one, one, one, one};
    const f32x4 zf = {0.f, 0.f, 0.f, 0.f};

    f32x4 oacc[4][2] = {{{0,0,0,0},{0,0,0,0}},{{0,0,0,0},{0,0,0,0}},
                        {{0,0,0,0},{0,0,0,0}},{{0,0,0,0},{0,0,0,0}}};
    f32x4 rsac[4]    = {{0,0,0,0},{0,0,0,0},{0,0,0,0},{0,0,0,0}};

    // preload K tile 0
    short8 ka[4];
#pragma unroll
    for (int i = 0; i < 4; ++i) ka[i] = *(const short8*)(Kg + i * 512);

    for (int kt = 0; kt < KPW; ++kt) {
        // V for THIS tile: consumed only after S-MFMA+exp chain (latency self-hiding)
        short8 vb[2][2];
#pragma unroll
        for (int c = 0; c < 2; ++c)
#pragma unroll
            for (int h = 0; h < 2; ++h)
                vb[c][h] = *(const short8*)(Vg + (size_t)kt * 2048 + h * 1024 + c * 32);
        // K for NEXT tile
        short8 kan[4];
        if (kt + 1 < KPW) {
            const u16* Kp2 = Kg + (size_t)(kt + 1) * 2048;
#pragma unroll
            for (int i = 0; i < 4; ++i) kan[i] = *(const short8*)(Kp2 + i * 512);
        }

#pragma unroll
        for (int t2 = 0; t2 < 4; ++t2) {
            f32x4 sf[4];
#pragma unroll
            for (int i = 0; i < 4; ++i)
                sf[i] = __builtin_amdgcn_mfma_f32_16x16x32_bf16(ka[i], qf[t2], zf, 0, 0, 0);
            u32 pk[4][2];
#pragma unroll
            for (int i = 0; i < 4; ++i) {
                pk[i][0] = pkfast(fexp2(fmaxf(sf[i][0], 0.f)), fexp2(fmaxf(sf[i][1], 0.f)));
                pk[i][1] = pkfast(fexp2(fmaxf(sf[i][2], 0.f)), fexp2(fmaxf(sf[i][3], 0.f)));
            }
#pragma unroll
            for (int c = 0; c < 2; ++c) {
                union { short8 s; u32 u[4]; } pa;
                pa.u[0] = pk[2 * c][0];     pa.u[1] = pk[2 * c][1];
                pa.u[2] = pk[2 * c + 1][0]; pa.u[3] = pk[2 * c + 1][1];
                oacc[t2][0] = __builtin_amdgcn_mfma_f32_16x16x32_bf16(pa.s, vb[c][0], oacc[t2][0], 0, 0, 0);
                oacc[t2][1] = __builtin_amdgcn_mfma_f32_16x16x32_bf16(pa.s, vb[c][1], oacc[t2][1], 0, 0, 0);
                rsac[t2]    = __builtin_amdgcn_mfma_f32_16x16x32_bf16(pa.s, vones,    rsac[t2],    0, 0, 0);
            }
        }

        if (kt + 1 < KPW) {
#pragma unroll
            for (int i = 0; i < 4; ++i) ka[i] = kan[i];
        }
    }

    // two-phase epilogue: pass 0 handles t2={0,1} (reducers: waves 0,1),
    // pass 1 handles t2={2,3} (reducers: waves 2,3). Reducer wave w always owns t2==w.
#pragma unroll
    for (int pass = 0; pass < 2; ++pass) {
        if (pass) __syncthreads();   // protect cmb overwrite until pass-0 reducers done
        {
            float* my = &cmb[w][lane][0];
#pragma unroll
            for (int tt = 0; tt < 2; ++tt) {
                const int t2 = pass * 2 + tt;
#pragma unroll
                for (int h = 0; h < 2; ++h)
#pragma unroll
                    for (int r = 0; r < 4; ++r) my[tt * 12 + h * 4 + r] = oacc[t2][h][r];
#pragma unroll
                for (int r = 0; r < 4; ++r) my[tt * 12 + 8 + r] = rsac[t2][r];
            }
        }
        __syncthreads();
        if ((w >> 1) == pass) {
            const int t2 = w;            // == pass*2 + (w&1)
            const int tt = w & 1;
            float o0[4] = {0,0,0,0}, o1[4] = {0,0,0,0}, rsum[4] = {0,0,0,0};
#pragma unroll
            for (int j = 0; j < 4; ++j) {
                const float* srcp = &cmb[j][lane][tt * 12];
#pragma unroll
                for (int r = 0; r < 4; ++r) {
                    o0[r]   += srcp[r];
                    o1[r]   += srcp[4 + r];
                    rsum[r] += srcp[8 + r];
                }
            }
            u16* Xb = X + (size_t)b * NSP * NCH + head * HD;
#pragma unroll
            for (int r = 0; r < 4; ++r) {
                const float inv = 1.f / rsum[r];
                u16* row = Xb + (size_t)(qbase + t2 * 16 + quad * 4 + r) * NCH;
                row[l15]      = f2bf(o0[r] * inv);
                row[16 + l15] = f2bf(o1[r] * inv);
            }
        }
    }
}

// ---------------- 1x1 conv: out[b,o,n] = sum_c W[o,c] X[b,n,c] + bias[o] ----------------
// grid (NSP/32, NCH/64, NB), block 256 (4 waves): wave w does o-tile blockIdx.y*64+w*16,
// all 4 waves share the same 32-row X tile -> L1 reuse (was 4 separate 1-wave blocks).
__global__ __launch_bounds__(256) void proj_kernel(
    const u16* __restrict__ Wb, const u16* __restrict__ X,
    const float* __restrict__ bias, float* __restrict__ out)
{
    const int b = blockIdx.z;
    const int w = threadIdx.x >> 6, lane = threadIdx.x & 63;
    const int l15 = lane & 15, quad = lane >> 4;
    const int obase = blockIdx.y * 64 + w * 16;
    const int nbase = blockIdx.x * 32;

    const u16* wrow = Wb + (size_t)(obase + l15) * NCH + quad * 8;
    const u16* xrow = X + ((size_t)b * NSP + nbase + l15) * NCH + quad * 8;

    f32x4 acc[2] = {{0,0,0,0},{0,0,0,0}};
#pragma unroll
    for (int ks = 0; ks < 8; ++ks) {
        const short8 af = *(const short8*)(wrow + ks * 32);
        acc[0] = __builtin_amdgcn_mfma_f32_16x16x32_bf16(af, *(const short8*)(xrow + ks * 32), acc[0], 0, 0, 0);
        acc[1] = __builtin_amdgcn_mfma_f32_16x16x32_bf16(af, *(const short8*)(xrow + (size_t)16 * NCH + ks * 32), acc[1], 0, 0, 0);
    }
#pragma unroll
    for (int r = 0; r < 4; ++r) {
        const int o = obase + quad * 4 + r;
        const float bo = bias[o];
        float* orow = out + ((size_t)b * NCH + o) * NSP + nbase;
        orow[l15]      = acc[0][r] + bo;
        orow[16 + l15] = acc[1][r] + bo;
    }
}

extern "C" void kernel_launch(void* const* d_in, const int* in_sizes, int n_in,
                              void* d_out, int out_size, void* d_ws, size_t ws_size,
                              hipStream_t stream) {
    const float* qkv   = (const float*)d_in[0];
    const float* temp  = (const float*)d_in[1];
    const float* projw = (const float*)d_in[2];
    const float* projb = (const float*)d_in[3];
    float* out = (float*)d_out;

    // workspace: Qn | Kn | Vp | X (each 2,359,296 bf16) | Wb (65,536 bf16)  ~19 MB
    u16* Qn = (u16*)d_ws;
    u16* Kn = Qn + (size_t)NBH * NSP * HD;
    u16* Vp = Kn + (size_t)NBH * NSP * HD;
    u16* X  = Vp + (size_t)NBH * NSP * HD;
    u16* Wb = X + (size_t)NB * NSP * NCH;

    prep_kernel<<<dim3(6, 4, NBH), dim3(192), 0, stream>>>(qkv, temp, projw, Qn, Kn, Vp, Wb);
    attn_kernel<<<dim3(NBH, NSP / 64), dim3(256), 0, stream>>>(Qn, Kn, Vp, X);
    proj_kernel<<<dim3(NSP / 32, NCH / 64, NB), dim3(256), 0, stream>>>(Wb, X, projb, out);
}

// Round 2
// 151.197 us; speedup vs baseline: 1.0799x; 1.0799x over previous
//
#include <hip/hip_runtime.h>

typedef unsigned short u16;
typedef unsigned int   u32;
typedef __attribute__((ext_vector_type(8))) short short8;   // 8 bf16 = 4 VGPRs
typedef __attribute__((ext_vector_type(4))) float f32x4;

#define NB    4      // batch
#define NCH   256    // channels
#define NHD   8      // heads
#define HD    32     // head dim
#define NSP   2304   // H*W
#define NBH   32     // NB*NHD
#define NKT   36     // total 64-wide K tiles
#define KPW   9      // K tiles per wave (4-wave in-block k-split)

// round-to-nearest-even fp32 -> bf16 bits
__device__ __forceinline__ u16 f2bf(float f) {
    u32 u = __float_as_uint(f);
    u += 0x7FFFu + ((u >> 16) & 1u);
    return (u16)(u >> 16);
}
__device__ __forceinline__ u32 pack2(float a, float b) {
    return (u32)f2bf(a) | ((u32)f2bf(b) << 16);
}
// fast pack two fp32 -> bf16x2: hw cvt (RNE) if present, else 1-instr v_perm truncate.
__device__ __forceinline__ u32 pkfast(float a, float b) {
#if __has_builtin(__builtin_amdgcn_cvt_pk_bf16_f32)
    typedef __attribute__((ext_vector_type(2))) __bf16 bf2;
    union { bf2 v; u32 u; } cv;
    cv.v = __builtin_amdgcn_cvt_pk_bf16_f32(a, b);
    return cv.u;
#else
    return __builtin_amdgcn_perm(__float_as_uint(b), __float_as_uint(a), 0x07060302u);
#endif
}
__device__ __forceinline__ float fexp2(float x) {
#if __has_builtin(__builtin_amdgcn_exp2f)
    return __builtin_amdgcn_exp2f(x);
#else
    return exp2f(x);
#endif
}

// ---------------- prep: normalize q,k (temp*log2e folded into q); v -> sigma-permuted
// tiles; p==3 slice casts proj_w -> bf16.
// Two spatial columns per thread (float2 loads halve VMEM instr count vs scalar).
// grid (6, 4, NBH), block 192: 6*192*2 = 2304 = NSP.
__global__ __launch_bounds__(192) void prep_kernel(
    const float* __restrict__ qkv, const float* __restrict__ temp,
    const float* __restrict__ projw,
    u16* __restrict__ Qn, u16* __restrict__ Kn, u16* __restrict__ Vp,
    u16* __restrict__ Wb)
{
    const int p  = blockIdx.y;
    const int bh = blockIdx.z, b = bh >> 3, head = bh & 7;

    if (p == 3) {   // proj_w cast: 16384 float4 chunks spread over 6*32 blocks
        const int idx = (bh * 6 + blockIdx.x) * 192 + threadIdx.x;
        if (idx < NCH * NCH / 4) {
            float4 v = ((const float4*)projw)[idx];
            ((uint2*)Wb)[idx] = make_uint2(pack2(v.x, v.y), pack2(v.z, v.w));
        }
        return;
    }

    const int i  = blockIdx.x * 192 + threadIdx.x;   // [0, 1152)
    const int n0 = i * 2;                            // even spatial index; pair (n0, n0+1)
    const float* src = qkv + ((size_t)(b * 3 * NCH + p * NCH + head * HD)) * NSP + n0;

    float2 v[HD];
#pragma unroll
    for (int d = 0; d < HD; ++d) v[d] = *(const float2*)(src + (size_t)d * NSP);

    if (p == 2) {
        // V tile layout: Vp[bh][kt][d*64 + c*32 + quad*8 + jj]; for even n0 the pair
        // (n0, n0+1) maps to adjacent u16 slots (jj even -> jj, jj+1 in the same
        // c/quad; proven over all even loc in [0,62]) -> one aligned u32 store.
        const int tile = n0 >> 6, loc = n0 & 63;
        const int c = loc >> 5, r5 = loc & 31;
        const int qd  = (r5 < 16) ? (r5 >> 2) : ((r5 - 16) >> 2);
        const int jj  = (r5 < 16) ? (r5 & 3) : (4 + (r5 & 3));
        u16* dst = Vp + (size_t)bh * NSP * HD + (size_t)tile * 2048 + c * 32 + qd * 8 + jj;
#pragma unroll
        for (int d = 0; d < HD; ++d) *(u32*)(dst + d * 64) = pack2(v[d].x, v[d].y);
    } else {
        float s0 = 0.f, s1 = 0.f;
#pragma unroll
        for (int d = 0; d < HD; ++d) { s0 += v[d].x * v[d].x; s1 += v[d].y * v[d].y; }
        float sc0 = 1.f / fmaxf(sqrtf(s0), 1e-12f);
        float sc1 = 1.f / fmaxf(sqrtf(s1), 1e-12f);
        if (p == 0) {   // fold temp*log2e into q
            const float t = temp[head] * 1.44269504088896f;
            sc0 *= t; sc1 *= t;
        }
        u32 pk[HD];   // [0..15] row n0, [16..31] row n0+1
#pragma unroll
        for (int j = 0; j < HD / 2; ++j) pk[j]          = pack2(v[2 * j].x * sc0, v[2 * j + 1].x * sc0);
#pragma unroll
        for (int j = 0; j < HD / 2; ++j) pk[HD / 2 + j] = pack2(v[2 * j].y * sc1, v[2 * j + 1].y * sc1);
        u16* dst = (p == 0 ? Qn : Kn) + ((size_t)bh * NSP + n0) * HD;   // 2 rows = 128 B contiguous
#pragma unroll
        for (int j = 0; j < 8; ++j) ((uint4*)dst)[j] = ((const uint4*)pk)[j];
    }
}

// ---------------- flash attention: 64 q-rows/wave, 4-way k-split, barrier-free K-loop ----
// block = 256 thr (4 waves), grid (NBH, NSP/64). blockIdx.x = bh so all q-blocks of a bh
// share one XCD -> K/V L2-resident.
// All 4 waves own the SAME 64 q-rows; wave w covers k-tiles [w*9,w*9+9).
// Partials combine linearly (exp(relu)/sum: no running max).
// Epilogue is TWO-PHASE to halve LDS (50176 -> 25600 B): publish+reduce t2={0,1}, barrier,
// publish+reduce t2={2,3}.
// NOTE: plain __launch_bounds__(256) — the (256,4) min-waves hint forced a 64-VGPR
// allocation with scratch spills (+35 MB HBM traffic, attn 54->71 us). Natural alloc
// is ~104 VGPR (<=128 -> 4 waves/SIMD), and LDS 25600 allows 6 blocks/CU, so the
// effective cap is 4 blocks/CU = 16 waves/CU with zero spills.
__global__ __launch_bounds__(256) void attn_kernel(
    const u16* __restrict__ Qn, const u16* __restrict__ Kn,
    const u16* __restrict__ Vp, u16* __restrict__ X)
{
    __shared__ float cmb[4][64][25];   // [wave][lane][tt*12 + {8 O0,O1 | 4 rs}] pad 25
    const int bh = blockIdx.x, b = bh >> 3, head = bh & 7;
    const int w = threadIdx.x >> 6, lane = threadIdx.x & 63;
    const int l15 = lane & 15, quad = lane >> 4;
    const int qbase = blockIdx.y * 64;

    const u16* Kg = Kn + (size_t)bh * NSP * HD + (size_t)w * KPW * 2048 + l15 * HD + quad * 8;
    const u16* Vg = Vp + (size_t)bh * NSP * HD + (size_t)w * KPW * 2048 + l15 * 64 + quad * 8;

    short8 qf[4];
#pragma unroll
    for (int t2 = 0; t2 < 4; ++t2)
        qf[t2] = *(const short8*)(Qn + ((size_t)bh * NSP + qbase + t2 * 16 + l15) * HD + quad * 8);

    const short one = (short)0x3F80;   // bf16 1.0
    const short8 vones = {one, one, one, one, one, one, one, one};
    const f32x4 zf = {0.f, 0.f, 0.f, 0.f};

    f32x4 oacc[4][2] = {{{0,0,0,0},{0,0,0,0}},{{0,0,0,0},{0,0,0,0}},
                        {{0,0,0,0},{0,0,0,0}},{{0,0,0,0},{0,0,0,0}}};
    f32x4 rsac[4]    = {{0,0,0,0},{0,0,0,0},{0,0,0,0},{0,0,0,0}};

    // preload K tile 0
    short8 ka[4];
#pragma unroll
    for (int i = 0; i < 4; ++i) ka[i] = *(const short8*)(Kg + i * 512);

    for (int kt = 0; kt < KPW; ++kt) {
        // V for THIS tile: consumed only after S-MFMA+exp chain (latency self-hiding)
        short8 vb[2][2];
#pragma unroll
        for (int c = 0; c < 2; ++c)
#pragma unroll
            for (int h = 0; h < 2; ++h)
                vb[c][h] = *(const short8*)(Vg + (size_t)kt * 2048 + h * 1024 + c * 32);
        // K for NEXT tile
        short8 kan[4];
        if (kt + 1 < KPW) {
            const u16* Kp2 = Kg + (size_t)(kt + 1) * 2048;
#pragma unroll
            for (int i = 0; i < 4; ++i) kan[i] = *(const short8*)(Kp2 + i * 512);
        }

#pragma unroll
        for (int t2 = 0; t2 < 4; ++t2) {
            f32x4 sf[4];
#pragma unroll
            for (int i = 0; i < 4; ++i)
                sf[i] = __builtin_amdgcn_mfma_f32_16x16x32_bf16(ka[i], qf[t2], zf, 0, 0, 0);
            u32 pk[4][2];
#pragma unroll
            for (int i = 0; i < 4; ++i) {
                pk[i][0] = pkfast(fexp2(fmaxf(sf[i][0], 0.f)), fexp2(fmaxf(sf[i][1], 0.f)));
                pk[i][1] = pkfast(fexp2(fmaxf(sf[i][2], 0.f)), fexp2(fmaxf(sf[i][3], 0.f)));
            }
#pragma unroll
            for (int c = 0; c < 2; ++c) {
                union { short8 s; u32 u[4]; } pa;
                pa.u[0] = pk[2 * c][0];     pa.u[1] = pk[2 * c][1];
                pa.u[2] = pk[2 * c + 1][0]; pa.u[3] = pk[2 * c + 1][1];
                oacc[t2][0] = __builtin_amdgcn_mfma_f32_16x16x32_bf16(pa.s, vb[c][0], oacc[t2][0], 0, 0, 0);
                oacc[t2][1] = __builtin_amdgcn_mfma_f32_16x16x32_bf16(pa.s, vb[c][1], oacc[t2][1], 0, 0, 0);
                rsac[t2]    = __builtin_amdgcn_mfma_f32_16x16x32_bf16(pa.s, vones,    rsac[t2],    0, 0, 0);
            }
        }

        if (kt + 1 < KPW) {
#pragma unroll
            for (int i = 0; i < 4; ++i) ka[i] = kan[i];
        }
    }

    // two-phase epilogue: pass 0 handles t2={0,1} (reducers: waves 0,1),
    // pass 1 handles t2={2,3} (reducers: waves 2,3). Reducer wave w always owns t2==w.
#pragma unroll
    for (int pass = 0; pass < 2; ++pass) {
        if (pass) __syncthreads();   // protect cmb overwrite until pass-0 reducers done
        {
            float* my = &cmb[w][lane][0];
#pragma unroll
            for (int tt = 0; tt < 2; ++tt) {
                const int t2 = pass * 2 + tt;
#pragma unroll
                for (int h = 0; h < 2; ++h)
#pragma unroll
                    for (int r = 0; r < 4; ++r) my[tt * 12 + h * 4 + r] = oacc[t2][h][r];
#pragma unroll
                for (int r = 0; r < 4; ++r) my[tt * 12 + 8 + r] = rsac[t2][r];
            }
        }
        __syncthreads();
        if ((w >> 1) == pass) {
            const int t2 = w;            // == pass*2 + (w&1)
            const int tt = w & 1;
            float o0[4] = {0,0,0,0}, o1[4] = {0,0,0,0}, rsum[4] = {0,0,0,0};
#pragma unroll
            for (int j = 0; j < 4; ++j) {
                const float* srcp = &cmb[j][lane][tt * 12];
#pragma unroll
                for (int r = 0; r < 4; ++r) {
                    o0[r]   += srcp[r];
                    o1[r]   += srcp[4 + r];
                    rsum[r] += srcp[8 + r];
                }
            }
            u16* Xb = X + (size_t)b * NSP * NCH + head * HD;
#pragma unroll
            for (int r = 0; r < 4; ++r) {
                const float inv = 1.f / rsum[r];
                u16* row = Xb + (size_t)(qbase + t2 * 16 + quad * 4 + r) * NCH;
                row[l15]      = f2bf(o0[r] * inv);
                row[16 + l15] = f2bf(o1[r] * inv);
            }
        }
    }
}

// ---------------- 1x1 conv: out[b,o,n] = sum_c W[o,c] X[b,n,c] + bias[o] ----------------
// grid (NSP/32, NCH/64, NB), block 256 (4 waves): wave w does o-tile blockIdx.y*64+w*16,
// all 4 waves share the same 32-row X tile -> L1 reuse (was 4 separate 1-wave blocks).
__global__ __launch_bounds__(256) void proj_kernel(
    const u16* __restrict__ Wb, const u16* __restrict__ X,
    const float* __restrict__ bias, float* __restrict__ out)
{
    const int b = blockIdx.z;
    const int w = threadIdx.x >> 6, lane = threadIdx.x & 63;
    const int l15 = lane & 15, quad = lane >> 4;
    const int obase = blockIdx.y * 64 + w * 16;
    const int nbase = blockIdx.x * 32;

    const u16* wrow = Wb + (size_t)(obase + l15) * NCH + quad * 8;
    const u16* xrow = X + ((size_t)b * NSP + nbase + l15) * NCH + quad * 8;

    f32x4 acc[2] = {{0,0,0,0},{0,0,0,0}};
#pragma unroll
    for (int ks = 0; ks < 8; ++ks) {
        const short8 af = *(const short8*)(wrow + ks * 32);
        acc[0] = __builtin_amdgcn_mfma_f32_16x16x32_bf16(af, *(const short8*)(xrow + ks * 32), acc[0], 0, 0, 0);
        acc[1] = __builtin_amdgcn_mfma_f32_16x16x32_bf16(af, *(const short8*)(xrow + (size_t)16 * NCH + ks * 32), acc[1], 0, 0, 0);
    }
#pragma unroll
    for (int r = 0; r < 4; ++r) {
        const int o = obase + quad * 4 + r;
        const float bo = bias[o];
        float* orow = out + ((size_t)b * NCH + o) * NSP + nbase;
        orow[l15]      = acc[0][r] + bo;
        orow[16 + l15] = acc[1][r] + bo;
    }
}

extern "C" void kernel_launch(void* const* d_in, const int* in_sizes, int n_in,
                              void* d_out, int out_size, void* d_ws, size_t ws_size,
                              hipStream_t stream) {
    const float* qkv   = (const float*)d_in[0];
    const float* temp  = (const float*)d_in[1];
    const float* projw = (const float*)d_in[2];
    const float* projb = (const float*)d_in[3];
    float* out = (float*)d_out;

    // workspace: Qn | Kn | Vp | X (each 2,359,296 bf16) | Wb (65,536 bf16)  ~19 MB
    u16* Qn = (u16*)d_ws;
    u16* Kn = Qn + (size_t)NBH * NSP * HD;
    u16* Vp = Kn + (size_t)NBH * NSP * HD;
    u16* X  = Vp + (size_t)NBH * NSP * HD;
    u16* Wb = X + (size_t)NB * NSP * NCH;

    prep_kernel<<<dim3(6, 4, NBH), dim3(192), 0, stream>>>(qkv, temp, projw, Qn, Kn, Vp, Wb);
    attn_kernel<<<dim3(NBH, NSP / 64), dim3(256), 0, stream>>>(Qn, Kn, Vp, X);
    proj_kernel<<<dim3(NSP / 32, NCH / 64, NB), dim3(256), 0, stream>>>(Wb, X, projb, out);
}